// Round 2
// baseline (103.507 us; speedup 1.0000x reference)
//
#include <hip/hip_runtime.h>

// Reference:
//   num_trues = sum(evict_mask, axis=1); num_false = 128 - num_trues
//   start = floordiv(seq_len + num_false - 1, page) * page - seq_len
//   end   = min(start + page, 128); start_c = max(start, 0)
//   out[t] = (t >= start_c && t < end) ? 0 : evict_mask[t]
//
// B = 524288, D = 128. One 32-lane group per row, int4 in / int4 out.
// bool input and output are both stored as int32 0/1 by the harness
// (round-1 absmax 0x3F800000-1 proved the int32 read path).

__global__ __launch_bounds__(256) void evict_range_kernel(
    const int* __restrict__ seq_lens,
    const int* __restrict__ evict_mask,
    const int* __restrict__ page_size_p,
    int* __restrict__ out,
    int batch)
{
    const int page = *page_size_p;           // uniform scalar load
    const int lane32 = threadIdx.x & 31;     // lane within 32-group
    const int tid = blockIdx.x * blockDim.x + threadIdx.x;
    const int group = tid >> 5;              // one group == one row
    const int ngroups = (gridDim.x * blockDim.x) >> 5;

    for (int row = group; row < batch; row += ngroups) {
        // coalesced 16B/lane load of this row's 128 mask words
        const int4* mrow = reinterpret_cast<const int4*>(evict_mask) + (size_t)row * 32;
        int4 v = mrow[lane32];
        int c0 = (v.x != 0) ? 1 : 0;
        int c1 = (v.y != 0) ? 1 : 0;
        int c2 = (v.z != 0) ? 1 : 0;
        int c3 = (v.w != 0) ? 1 : 0;

        int cnt = c0 + c1 + c2 + c3;
        #pragma unroll
        for (int off = 1; off < 32; off <<= 1)
            cnt += __shfl_xor(cnt, off, 32);     // num_trues for this row

        int sl = seq_lens[row];                  // broadcast within group
        int num_false = 128 - cnt;
        int s = sl + num_false - 1;
        // floor division (reference is jnp floor_divide; s can be -1)
        int q = s / page;
        if (s < 0 && (s % page) != 0) q--;
        int start = q * page - sl;
        int sc  = start > 0 ? start : 0;
        int end = start + page;
        if (end > 128) end = 128;

        int t0 = lane32 * 4;
        int4 o;
        o.x = (t0 + 0 >= sc && t0 + 0 < end) ? 0 : c0;
        o.y = (t0 + 1 >= sc && t0 + 1 < end) ? 0 : c1;
        o.z = (t0 + 2 >= sc && t0 + 2 < end) ? 0 : c2;
        o.w = (t0 + 3 >= sc && t0 + 3 < end) ? 0 : c3;
        reinterpret_cast<int4*>(out)[(size_t)row * 32 + lane32] = o;
    }
}

extern "C" void kernel_launch(void* const* d_in, const int* in_sizes, int n_in,
                              void* d_out, int out_size, void* d_ws, size_t ws_size,
                              hipStream_t stream) {
    const int* seq_lens   = (const int*)d_in[0];
    const int* evict_mask = (const int*)d_in[1];
    const int* page_size  = (const int*)d_in[2];
    int* out = (int*)d_out;
    const int batch = in_sizes[0];

    // 8192 blocks x 256 threads -> 65536 row-groups, grid-stride over 524288 rows
    const int blocks = 8192;
    evict_range_kernel<<<blocks, 256, 0, stream>>>(seq_lens, evict_mask, page_size, out, batch);
}

// Round 3
// 94.641 us; speedup vs baseline: 1.0937x; 1.0937x over previous
//
#include <hip/hip_runtime.h>

// Reference:
//   num_trues = sum(evict_mask, axis=1); num_false = 128 - num_trues
//   start = floordiv(seq_len + num_false - 1, page) * page - seq_len
//   end   = min(start + page, 128); start_c = max(start, 0)
//   out[t] = (t >= start_c && t < end) ? 0 : evict_mask[t]
//
// B = 524288, D = 128. One 32-lane group per row (wave64 = 2 rows).
// bool in/out stored as int32 0/1 (proven round 1: absmax == 0x3F800000-1).
//
// Row-sum via 4x __ballot + popcount of the wave-half instead of a 5-step
// dependent __shfl_xor chain (ds_bpermute latency ~30cyc each, serialized).

typedef int vint4 __attribute__((ext_vector_type(4)));

__global__ __launch_bounds__(256) void evict_range_kernel(
    const int* __restrict__ seq_lens,
    const int* __restrict__ evict_mask,
    const int* __restrict__ page_size_p,
    int* __restrict__ out,
    int batch)
{
    const int page = *page_size_p;                 // uniform scalar
    const int lane32 = threadIdx.x & 31;           // lane within row-group
    const unsigned half_shift = threadIdx.x & 32;  // 0 = low half, 32 = high half
    const int tid = blockIdx.x * blockDim.x + threadIdx.x;
    const int group = tid >> 5;                    // one group == one row
    const int ngroups = (gridDim.x * blockDim.x) >> 5;

    for (int row = group; row < batch; row += ngroups) {
        // coalesced 16B/lane nontemporal load of this row's 128 mask words
        const vint4* mrow = reinterpret_cast<const vint4*>(evict_mask) + (size_t)row * 32;
        vint4 v = __builtin_nontemporal_load(&mrow[lane32]);

        // wave-wide ballots: bits 0-31 = row of lanes 0-31, bits 32-63 = other row
        unsigned long long b0 = __ballot(v.x != 0);
        unsigned long long b1 = __ballot(v.y != 0);
        unsigned long long b2 = __ballot(v.z != 0);
        unsigned long long b3 = __ballot(v.w != 0);
        int cnt = __popc((unsigned)(b0 >> half_shift))
                + __popc((unsigned)(b1 >> half_shift))
                + __popc((unsigned)(b2 >> half_shift))
                + __popc((unsigned)(b3 >> half_shift));   // num_trues of MY row

        int sl = seq_lens[row];
        int num_false = 128 - cnt;
        int s = sl + num_false - 1;
        // floor division (s can be -1 when sl==0, cnt==128)
        int q = s / page;
        if (s < 0 && (s % page) != 0) q--;
        int start = q * page - sl;
        int sc  = start > 0 ? start : 0;
        int end = start + page;
        if (end > 128) end = 128;

        int t0 = lane32 * 4;
        vint4 o;
        o.x = (t0 + 0 >= sc && t0 + 0 < end) ? 0 : ((v.x != 0) ? 1 : 0);
        o.y = (t0 + 1 >= sc && t0 + 1 < end) ? 0 : ((v.y != 0) ? 1 : 0);
        o.z = (t0 + 2 >= sc && t0 + 2 < end) ? 0 : ((v.z != 0) ? 1 : 0);
        o.w = (t0 + 3 >= sc && t0 + 3 < end) ? 0 : ((v.w != 0) ? 1 : 0);
        __builtin_nontemporal_store(o, reinterpret_cast<vint4*>(out) + (size_t)row * 32 + lane32);
    }
}

extern "C" void kernel_launch(void* const* d_in, const int* in_sizes, int n_in,
                              void* d_out, int out_size, void* d_ws, size_t ws_size,
                              hipStream_t stream) {
    const int* seq_lens   = (const int*)d_in[0];
    const int* evict_mask = (const int*)d_in[1];
    const int* page_size  = (const int*)d_in[2];
    int* out = (int*)d_out;
    const int batch = in_sizes[0];

    // 8192 blocks x 256 threads -> 65536 row-groups, 8 grid-stride iterations
    const int blocks = 8192;
    evict_range_kernel<<<blocks, 256, 0, stream>>>(seq_lens, evict_mask, page_size, out, batch);
}